// Round 7
// baseline (349.138 us; speedup 1.0000x reference)
//
#include <hip/hip_runtime.h>

typedef unsigned short u16;
typedef __bf16 bf16x8 __attribute__((ext_vector_type(8)));
typedef float f32x4 __attribute__((ext_vector_type(4)));

#define LAMBDA_INIT_F 0.7836057665f
#define ONE_MINUS_LI  0.2163942335f
// 0.125 * log2(e): folds the 1/sqrt(64) score scale AND the exp->exp2
// conversion into the Q values (bf16 relative precision unaffected).
#define Q_PRESCALE 0.1803368801f

__device__ __forceinline__ u16 f2bf(float f) {
  union { float f; unsigned u; } v; v.f = f;
  unsigned r = v.u + 0x7fffu + ((v.u >> 16) & 1u);
  return (u16)(r >> 16);
}

__device__ __forceinline__ float fast_exp2(float x) {
#if __has_builtin(__builtin_amdgcn_exp2f)
  return __builtin_amdgcn_exp2f(x);   // v_exp_f32: hardware exp2
#else
  return __builtin_exp2f(x);
#endif
}

__device__ __forceinline__ void gload_lds16(const void* g, void* l) {
  __builtin_amdgcn_global_load_lds(
      (const __attribute__((address_space(1))) void*)g,
      (__attribute__((address_space(3))) void*)l, 16, 0, 0);
}

// ---------------- cast x -> bf16 ----------------
__global__ __launch_bounds__(256) void cast_x_kernel(const float* __restrict__ x,
                                                     u16* __restrict__ xb) {
  const int i = (blockIdx.x * 256 + threadIdx.x) * 4;
  const float4 v = *(const float4*)(x + i);
  u16 tmp[4] = {f2bf(v.x), f2bf(v.y), f2bf(v.z), f2bf(v.w)};
  *(uint2*)(xb + i) = *(const uint2*)tmp;
}

// ------------- transpose-cast weights -------------
__global__ __launch_bounds__(256) void transpose_w_kernel(
    const float* __restrict__ Wq, const float* __restrict__ Wk,
    const float* __restrict__ Wv, const float* __restrict__ Wo,
    u16* __restrict__ WqkvT, u16* __restrict__ WoT) {
  __shared__ float t[32][33];
  const int z = blockIdx.z;
  const float* src = (z == 0) ? Wq : (z == 1) ? Wk : (z == 2) ? Wv : Wo;
  const int n0 = blockIdx.x * 32, k0 = blockIdx.y * 32;
  const int tx = threadIdx.x & 31, ty = threadIdx.x >> 5;
#pragma unroll
  for (int i = 0; i < 4; ++i)
    t[ty + i * 8][tx] = src[(size_t)(k0 + ty + i * 8) * 2048 + n0 + tx];
  __syncthreads();
  u16* dst = (z < 3) ? (WqkvT + ((size_t)z * 2048 + n0) * 2048 + k0)
                     : (WoT + (size_t)n0 * 2048 + k0);
#pragma unroll
  for (int i = 0; i < 4; ++i)
    dst[(size_t)(ty + i * 8) * 2048 + tx] = f2bf(t[tx][ty + i * 8]);
}

// ---------------- RoPE tables ----------------
__global__ __launch_bounds__(256) void rope_table_kernel(float* __restrict__ cosT,
                                                         float* __restrict__ sinT) {
  const int idx = blockIdx.x * 256 + threadIdx.x;  // S*32 = 65536
  const int s = idx >> 5, i = idx & 31;
  const float div = expf((float)(2 * i) * (-9.210340371976184f / 64.f));
  const float ang = (float)s * div;
  cosT[idx] = cosf(ang);
  sinT[idx] = sinf(ang);
}

// ---------------- lambda_full ----------------
__global__ void lambda_kernel(const float* __restrict__ lq1, const float* __restrict__ lk1,
                              const float* __restrict__ lq2, const float* __restrict__ lk2,
                              float* __restrict__ lam) {
  const int t = threadIdx.x;  // 64 threads
  float p1 = lq1[t] * lk1[t];
  float p2 = lq2[t] * lk2[t];
#pragma unroll
  for (int mk = 1; mk < 64; mk <<= 1) {
    p1 += __shfl_xor(p1, mk);
    p2 += __shfl_xor(p2, mk);
  }
  if (t == 0) *lam = expf(p1) - expf(p2) + LAMBDA_INIT_F;
}

// ---------------- GEMM: C(f32) = A(bf16, MxK) @ Bt(bf16, NxK)^T ----------------
// 128x128 tile, BK=64, 4 waves (2x2), each wave 64x64 via 4x4 16x16x32 MFMA.
// LDS rows are 128 B with chunk-XOR swizzle (proven 0-conflict pattern from
// attn): linear global_load_lds dest + inverse-swizzled global source +
// matching XOR on the fragment reads.
__global__ __launch_bounds__(256) void gemm_bt_kernel(
    const u16* __restrict__ A, const u16* __restrict__ Bt,
    float* __restrict__ C, int M, int N, int K) {
  __shared__ u16 As[128 * 64];
  __shared__ u16 Bs[128 * 64];
  const int tid = threadIdx.x;
  const int lane = tid & 63;
  const int w = tid >> 6;
  const int wm = w >> 1, wn = w & 1;
  const long m0 = (long)blockIdx.y * 128;
  const long n0 = (long)blockIdx.x * 128;

  f32x4 acc[4][4];
#pragma unroll
  for (int i = 0; i < 4; ++i)
#pragma unroll
    for (int j = 0; j < 4; ++j) acc[i][j] = f32x4{0.f, 0.f, 0.f, 0.f};

  const int sr = lane >> 3;                 // row within 8-row staging group
  const int scS = ((lane & 7) ^ sr) * 8;    // inverse-swizzled source col (elems)
  const int fr = lane & 15;
  const int kgrp = lane >> 4;
  const int swz = (fr & 7) << 3;            // read-side XOR (elems)

  // per-wave staging base pointers (stepped by BK each iteration)
  const u16* aSrc = A + (m0 + w * 32 + sr) * (long)K + scS;
  const u16* bSrc = Bt + (n0 + w * 32 + sr) * (long)K + scS;

  for (int k0 = 0; k0 < K; k0 += 64) {
#pragma unroll
    for (int g = 0; g < 4; ++g) {
      gload_lds16(aSrc + (size_t)g * 8 * K, &As[(w * 32 + g * 8) * 64]);
      gload_lds16(bSrc + (size_t)g * 8 * K, &Bs[(w * 32 + g * 8) * 64]);
    }
    aSrc += 64;
    bSrc += 64;
    __syncthreads();
#pragma unroll
    for (int ks = 0; ks < 2; ++ks) {
      bf16x8 af[4], bfr[4];
#pragma unroll
      for (int mi = 0; mi < 4; ++mi)
        af[mi] = *(const bf16x8*)&As[(wm * 64 + mi * 16 + fr) * 64 +
                                     ((ks * 32 + kgrp * 8) ^ swz)];
#pragma unroll
      for (int ni = 0; ni < 4; ++ni)
        bfr[ni] = *(const bf16x8*)&Bs[(wn * 64 + ni * 16 + fr) * 64 +
                                      ((ks * 32 + kgrp * 8) ^ swz)];
#pragma unroll
      for (int mi = 0; mi < 4; ++mi)
#pragma unroll
        for (int ni = 0; ni < 4; ++ni)
          acc[mi][ni] =
              __builtin_amdgcn_mfma_f32_16x16x32_bf16(af[mi], bfr[ni], acc[mi][ni], 0, 0, 0);
    }
    __syncthreads();
  }
  const int rg = (lane >> 4) * 4;
#pragma unroll
  for (int mi = 0; mi < 4; ++mi)
#pragma unroll
    for (int ni = 0; ni < 4; ++ni) {
      const long col = n0 + wn * 64 + ni * 16 + fr;
#pragma unroll
      for (int j = 0; j < 4; ++j) {
        const long row = m0 + wm * 64 + mi * 16 + rg + j;
        C[row * N + col] = acc[mi][ni][j];
      }
    }
}

// ---------------- RoPE apply (Q pre-scaled by 0.125*log2e) ----------------
__global__ __launch_bounds__(256) void rope_apply_kernel(
    const float* __restrict__ proj, const float* __restrict__ cosT,
    const float* __restrict__ sinT, u16* __restrict__ Qh, u16* __restrict__ Kh) {
  const int s = blockIdx.x;
  const int tid = threadIdx.x;
#pragma unroll
  for (int t = 0; t < 8; ++t) {
    const int p = t * 256 + tid;     // 0..2047
    const int isK = p >> 10;
    const int pp = p & 1023;
    const int hh = pp >> 5, i = pp & 31;
    const float* src = proj + (size_t)s * 6144 + isK * 2048 + hh * 64 + 2 * i;
    const float x1 = src[0], x2 = src[1];
    const float c = cosT[s * 32 + i], sn = sinT[s * 32 + i];
    const float scl = isK ? 1.0f : Q_PRESCALE;
    u16* dst = (isK ? Kh : Qh) + ((size_t)hh * 2048 + s) * 64 + 2 * i;
    dst[0] = f2bf((x1 * c - x2 * sn) * scl);
    dst[1] = f2bf((x1 * sn + x2 * c) * scl);
  }
}

// ------------- transpose-cast V -------------
__global__ __launch_bounds__(256) void transpose_v_kernel(const float* __restrict__ proj,
                                                          u16* __restrict__ Vt) {
  __shared__ float t[32][33];
  const int s0 = blockIdx.x * 32, r0 = blockIdx.y * 32;
  const int tx = threadIdx.x & 31, ty = threadIdx.x >> 5;
#pragma unroll
  for (int i = 0; i < 4; ++i)
    t[ty + i * 8][tx] = proj[(size_t)(s0 + ty + i * 8) * 6144 + 4096 + r0 + tx];
  __syncthreads();
#pragma unroll
  for (int i = 0; i < 4; ++i)
    Vt[(size_t)(r0 + ty + i * 8) * 2048 + s0 + tx] = f2bf(t[tx][ty + i * 8]);
}

// ---------------- flash attention (causal), dual streams ----------------
__global__ __launch_bounds__(256) void attn_kernel(
    const u16* __restrict__ Qh, const u16* __restrict__ Kh,
    const u16* __restrict__ Vt, float* __restrict__ attnOut) {
  __shared__ u16 Kt[2][64 * 64];   // [buf][key][d]   (chunk-swizzled)
  __shared__ u16 Vs[2][128 * 64];  // [buf][out-d][key] (chunk-swizzled)
  __shared__ __bf16 Ps[4 * 16 * 64];  // per-wave P staging (swizzled)
  const int tid = threadIdx.x, lane = tid & 63, w = tid >> 6;
  const int fr = lane & 15, kgrp = lane >> 4;
  const int bid = blockIdx.x;
  const int xcd = bid & 7, idx = bid >> 3;
  const int hh = xcd * 4 + (idx & 3);     // 4 head-streams per XCD group
  const int pairIdx = idx >> 2;           // 0..15
  const int h = hh >> 1, comp = hh & 1;
  const int q0A = pairIdx * 64, q0B = (31 - pairIdx) * 64;
  const int jmaxA = pairIdx, jmaxB = 31 - pairIdx;
  const int ntA = jmaxA + 1, ntot = ntA + jmaxB + 1;  // == 33

  const int sr = lane >> 3;
  const int scS = (((lane & 7) ^ sr) * 8);  // source-swizzled column (elems)
  const int swz = (fr & 7) << 3;            // read-side XOR (elems)

  bf16x8 qf0, qf1;
  {
    const u16* qb = Qh + ((size_t)hh * 2048 + q0A + w * 16 + fr) * 64 + kgrp * 8;
    qf0 = *(const bf16x8*)qb;
    qf1 = *(const bf16x8*)(qb + 32);
  }
  bf16x8 onesf;
#pragma unroll
  for (int i = 0; i < 8; ++i) onesf[i] = (__bf16)1.0f;

  // o[0..7] = output d-frags; o[8] = row-sum accumulator (ones-MFMA)
  f32x4 o[9];
#pragma unroll
  for (int i = 0; i < 9; ++i) o[i] = f32x4{0.f, 0.f, 0.f, 0.f};
  float m_r[4] = {-1e30f, -1e30f, -1e30f, -1e30f};

  auto stage = [&](int b, int kv0) {
#pragma unroll
    for (int i = 0; i < 2; ++i)
      gload_lds16(Kh + ((size_t)hh * 2048 + kv0 + i * 32 + w * 8 + sr) * 64 + scS,
                  &Kt[b][(i * 32 + w * 8) * 64]);
#pragma unroll
    for (int i = 0; i < 4; ++i)
      gload_lds16(Vt + ((size_t)h * 128 + i * 32 + w * 8 + sr) * 2048 + kv0 + scS,
                  &Vs[b][(i * 32 + w * 8) * 64]);
  };

  auto writeOut = [&](int q0) {
    float* outp = attnOut + (size_t)comp * (2048 * 2048);
#pragma unroll
    for (int j = 0; j < 4; ++j) {
      const int row = q0 + w * 16 + kgrp * 4 + j;
      const float inv = 1.0f / o[8][j];
      float* op = outp + (size_t)row * 2048 + h * 128;
#pragma unroll
      for (int nf = 0; nf < 8; ++nf) op[nf * 16 + fr] = o[nf][j] * inv;
    }
  };

  stage(0, 0);
  __syncthreads();

  for (int t = 0; t < ntot; ++t) {
    const int cur = t & 1;
    if (t + 1 < ntot) {
      const int nk = (t + 1 < ntA) ? (t + 1) * 64 : (t + 1 - ntA) * 64;
      stage(cur ^ 1, nk);
    }
    const bool inA = t < ntA;
    const int q0 = inA ? q0A : q0B;
    const int jj = inA ? t : t - ntA;
    const int kv0 = jj * 64;
    const bool diag = inA ? (jj == jmaxA) : (jj == jmaxB);

    // ---- QK^T (scores already scaled, exp2 domain) ----
    f32x4 s[4];
    __builtin_amdgcn_s_setprio(1);
#pragma unroll
    for (int nf = 0; nf < 4; ++nf) {
      s[nf] = f32x4{0.f, 0.f, 0.f, 0.f};
      const bf16x8 b0 = *(const bf16x8*)&Kt[cur][(nf * 16 + fr) * 64 + ((kgrp * 8) ^ swz)];
      const bf16x8 b1 =
          *(const bf16x8*)&Kt[cur][(nf * 16 + fr) * 64 + ((32 + kgrp * 8) ^ swz)];
      s[nf] = __builtin_amdgcn_mfma_f32_16x16x32_bf16(qf0, b0, s[nf], 0, 0, 0);
      s[nf] = __builtin_amdgcn_mfma_f32_16x16x32_bf16(qf1, b1, s[nf], 0, 0, 0);
    }
    __builtin_amdgcn_s_setprio(0);

    // ---- mask + row max ----
    float pmax[4] = {-1e30f, -1e30f, -1e30f, -1e30f};
    if (diag) {
#pragma unroll
      for (int nf = 0; nf < 4; ++nf) {
        const int key = kv0 + nf * 16 + fr;
#pragma unroll
        for (int j = 0; j < 4; ++j) {
          float sc2 = s[nf][j];
          if (key > q0 + w * 16 + kgrp * 4 + j) sc2 = -1e30f;
          s[nf][j] = sc2;
          pmax[j] = fmaxf(pmax[j], sc2);
        }
      }
    } else {
#pragma unroll
      for (int nf = 0; nf < 4; ++nf)
#pragma unroll
        for (int j = 0; j < 4; ++j) pmax[j] = fmaxf(pmax[j], s[nf][j]);
    }
#pragma unroll
    for (int j = 0; j < 4; ++j)
#pragma unroll
      for (int mk = 1; mk < 16; mk <<= 1) pmax[j] = fmaxf(pmax[j], __shfl_xor(pmax[j], mk));

    // ---- defer-rescale (exact: only when a row max grew) ----
    bool grow = false;
#pragma unroll
    for (int j = 0; j < 4; ++j) grow |= (pmax[j] > m_r[j]);
    if (__any(grow)) {
#pragma unroll
      for (int j = 0; j < 4; ++j) {
        const float mn = fmaxf(m_r[j], pmax[j]);
        const float sf = fast_exp2(m_r[j] - mn);
        m_r[j] = mn;
#pragma unroll
        for (int nf = 0; nf < 9; ++nf) o[nf][j] *= sf;
      }
    }

    // ---- exp2 + P staging (swizzled, native bf16 cast) ----
#pragma unroll
    for (int nf = 0; nf < 4; ++nf)
#pragma unroll
      for (int j = 0; j < 4; ++j) {
        const float p = fast_exp2(s[nf][j] - m_r[j]);
        const int prow = kgrp * 4 + j;
        Ps[w * 1024 + prow * 64 + ((nf * 16 + fr) ^ ((prow & 7) << 3))] = (__bf16)p;
      }

    // ---- PV (+ ones-MFMA row-sum into o[8]) ----
    const bf16x8 pa0 = *(const bf16x8*)&Ps[w * 1024 + fr * 64 + ((kgrp * 8) ^ swz)];
    const bf16x8 pa1 = *(const bf16x8*)&Ps[w * 1024 + fr * 64 + ((32 + kgrp * 8) ^ swz)];
    __builtin_amdgcn_s_setprio(1);
#pragma unroll
    for (int nf = 0; nf < 8; ++nf) {
      const bf16x8 v0 = *(const bf16x8*)&Vs[cur][(nf * 16 + fr) * 64 + ((kgrp * 8) ^ swz)];
      const bf16x8 v1 =
          *(const bf16x8*)&Vs[cur][(nf * 16 + fr) * 64 + ((32 + kgrp * 8) ^ swz)];
      o[nf] = __builtin_amdgcn_mfma_f32_16x16x32_bf16(pa0, v0, o[nf], 0, 0, 0);
      o[nf] = __builtin_amdgcn_mfma_f32_16x16x32_bf16(pa1, v1, o[nf], 0, 0, 0);
    }
    o[8] = __builtin_amdgcn_mfma_f32_16x16x32_bf16(pa0, onesf, o[8], 0, 0, 0);
    o[8] = __builtin_amdgcn_mfma_f32_16x16x32_bf16(pa1, onesf, o[8], 0, 0, 0);
    __builtin_amdgcn_s_setprio(0);

    // ---- sub-problem switch: flush A, reset state, load B's Q ----
    if (t == jmaxA) {
      writeOut(q0A);
#pragma unroll
      for (int i = 0; i < 9; ++i) o[i] = f32x4{0.f, 0.f, 0.f, 0.f};
#pragma unroll
      for (int j = 0; j < 4; ++j) m_r[j] = -1e30f;
      const u16* qb = Qh + ((size_t)hh * 2048 + q0B + w * 16 + fr) * 64 + kgrp * 8;
      qf0 = *(const bf16x8*)qb;
      qf1 = *(const bf16x8*)(qb + 32);
    }
    __syncthreads();
  }
  writeOut(q0B);
}

// ---------------- combine ----------------
__global__ __launch_bounds__(256) void combine_kernel(
    const float* __restrict__ attn, const float* __restrict__ lam,
    const float* __restrict__ g, u16* __restrict__ ab) {
  const int lane = threadIdx.x & 63;
  const int idx = blockIdx.x * 4 + (threadIdx.x >> 6);  // (s,h)
  const int s = idx >> 4, h = idx & 15;
  const float lf = *lam;
  const float* a1 = attn + (size_t)s * 2048 + h * 128;
  const float* a2 = a1 + (size_t)2048 * 2048;
  const float x0 = a1[lane] - lf * a2[lane];
  const float x1 = a1[lane + 64] - lf * a2[lane + 64];
  float ss = x0 * x0 + x1 * x1;
#pragma unroll
  for (int mk = 1; mk < 64; mk <<= 1) ss += __shfl_xor(ss, mk);
  const float r = rsqrtf(ss * (1.0f / 128.0f) + 1e-5f) * ONE_MINUS_LI;
  u16* op = ab + (size_t)s * 2048 + h * 128;
  op[lane] = f2bf(x0 * r * g[lane]);
  op[lane + 64] = f2bf(x1 * r * g[lane + 64]);
}

extern "C" void kernel_launch(void* const* d_in, const int* in_sizes, int n_in,
                              void* d_out, int out_size, void* d_ws, size_t ws_size,
                              hipStream_t stream) {
  const float* x = (const float*)d_in[0];
  const float* Wq = (const float*)d_in[1];
  const float* Wk = (const float*)d_in[2];
  const float* Wv = (const float*)d_in[3];
  const float* Wo = (const float*)d_in[4];
  const float* lq1 = (const float*)d_in[5];
  const float* lk1 = (const float*)d_in[6];
  const float* lq2 = (const float*)d_in[7];
  const float* lk2 = (const float*)d_in[8];
  const float* g = (const float*)d_in[9];
  float* out = (float*)d_out;

  char* ws = (char*)d_ws;
  u16* xb = (u16*)(ws);                                 // 8 MiB
  u16* WqkvT = (u16*)(ws + (size_t)(8u << 20));         // 24 MiB
  u16* WoT = (u16*)(ws + (size_t)(32u << 20));          // 8 MiB
  float* proj = (float*)(ws + (size_t)(40u << 20));     // 48 MiB (reused as attn)
  float* attn = proj;                                   // 32 MiB (attn1|attn2)
  u16* Qh = (u16*)(ws + (size_t)(88u << 20));           // 8 MiB
  u16* Kh = (u16*)(ws + (size_t)(96u << 20));           // 8 MiB
  u16* Vt = (u16*)(ws + (size_t)(104u << 20));          // 8 MiB
  u16* ab = (u16*)(ws + (size_t)(112u << 20));          // 8 MiB
  float* cosT = (float*)(ws + (size_t)(120u << 20));    // 256 KiB
  float* sinT = (float*)(ws + (size_t)(120u << 20) + (256u << 10));
  float* lam = (float*)(ws + (size_t)(120u << 20) + (512u << 10));

  cast_x_kernel<<<4096, 256, 0, stream>>>(x, xb);
  transpose_w_kernel<<<dim3(64, 64, 4), 256, 0, stream>>>(Wq, Wk, Wv, Wo, WqkvT, WoT);
  rope_table_kernel<<<256, 256, 0, stream>>>(cosT, sinT);
  lambda_kernel<<<1, 64, 0, stream>>>(lq1, lk1, lq2, lk2, lam);
  gemm_bt_kernel<<<dim3(48, 16), 256, 0, stream>>>(xb, WqkvT, proj, 2048, 6144, 2048);
  rope_apply_kernel<<<2048, 256, 0, stream>>>(proj, cosT, sinT, Qh, Kh);
  transpose_v_kernel<<<dim3(64, 64), 256, 0, stream>>>(proj, Vt);
  attn_kernel<<<512, 256, 0, stream>>>(Qh, Kh, Vt, attn);
  combine_kernel<<<8192, 256, 0, stream>>>(attn, lam, g, ab);
  gemm_bt_kernel<<<dim3(16, 16), 256, 0, stream>>>(ab, WoT, out, 2048, 2048, 2048);
}

// Round 8
// 338.813 us; speedup vs baseline: 1.0305x; 1.0305x over previous
//
#include <hip/hip_runtime.h>

typedef unsigned short u16;
typedef __bf16 bf16x8 __attribute__((ext_vector_type(8)));
typedef float f32x4 __attribute__((ext_vector_type(4)));

#define LAMBDA_INIT_F 0.7836057665f
#define ONE_MINUS_LI  0.2163942335f
// 0.125 * log2(e): folds the 1/sqrt(64) score scale AND the exp->exp2
// conversion into the Q values (bf16 relative precision unaffected).
#define Q_PRESCALE 0.1803368801f

__device__ __forceinline__ u16 f2bf(float f) {
  union { float f; unsigned u; } v; v.f = f;
  unsigned r = v.u + 0x7fffu + ((v.u >> 16) & 1u);
  return (u16)(r >> 16);
}

__device__ __forceinline__ float fast_exp2(float x) {
#if __has_builtin(__builtin_amdgcn_exp2f)
  return __builtin_amdgcn_exp2f(x);   // v_exp_f32: hardware exp2
#else
  return __builtin_exp2f(x);
#endif
}

__device__ __forceinline__ void gload_lds16(const void* g, void* l) {
  __builtin_amdgcn_global_load_lds(
      (const __attribute__((address_space(1))) void*)g,
      (__attribute__((address_space(3))) void*)l, 16, 0, 0);
}

// ---------------- cast x -> bf16 ----------------
__global__ __launch_bounds__(256) void cast_x_kernel(const float* __restrict__ x,
                                                     u16* __restrict__ xb) {
  const int i = (blockIdx.x * 256 + threadIdx.x) * 4;
  const float4 v = *(const float4*)(x + i);
  u16 tmp[4] = {f2bf(v.x), f2bf(v.y), f2bf(v.z), f2bf(v.w)};
  *(uint2*)(xb + i) = *(const uint2*)tmp;
}

// ------------- transpose-cast weights -------------
__global__ __launch_bounds__(256) void transpose_w_kernel(
    const float* __restrict__ Wq, const float* __restrict__ Wk,
    const float* __restrict__ Wv, const float* __restrict__ Wo,
    u16* __restrict__ WqkvT, u16* __restrict__ WoT) {
  __shared__ float t[32][33];
  const int z = blockIdx.z;
  const float* src = (z == 0) ? Wq : (z == 1) ? Wk : (z == 2) ? Wv : Wo;
  const int n0 = blockIdx.x * 32, k0 = blockIdx.y * 32;
  const int tx = threadIdx.x & 31, ty = threadIdx.x >> 5;
#pragma unroll
  for (int i = 0; i < 4; ++i)
    t[ty + i * 8][tx] = src[(size_t)(k0 + ty + i * 8) * 2048 + n0 + tx];
  __syncthreads();
  u16* dst = (z < 3) ? (WqkvT + ((size_t)z * 2048 + n0) * 2048 + k0)
                     : (WoT + (size_t)n0 * 2048 + k0);
#pragma unroll
  for (int i = 0; i < 4; ++i)
    dst[(size_t)(ty + i * 8) * 2048 + tx] = f2bf(t[tx][ty + i * 8]);
}

// ---------------- RoPE tables ----------------
__global__ __launch_bounds__(256) void rope_table_kernel(float* __restrict__ cosT,
                                                         float* __restrict__ sinT) {
  const int idx = blockIdx.x * 256 + threadIdx.x;  // S*32 = 65536
  const int s = idx >> 5, i = idx & 31;
  const float div = expf((float)(2 * i) * (-9.210340371976184f / 64.f));
  const float ang = (float)s * div;
  cosT[idx] = cosf(ang);
  sinT[idx] = sinf(ang);
}

// ---------------- lambda_full ----------------
__global__ void lambda_kernel(const float* __restrict__ lq1, const float* __restrict__ lk1,
                              const float* __restrict__ lq2, const float* __restrict__ lk2,
                              float* __restrict__ lam) {
  const int t = threadIdx.x;  // 64 threads
  float p1 = lq1[t] * lk1[t];
  float p2 = lq2[t] * lk2[t];
#pragma unroll
  for (int mk = 1; mk < 64; mk <<= 1) {
    p1 += __shfl_xor(p1, mk);
    p2 += __shfl_xor(p2, mk);
  }
  if (t == 0) *lam = expf(p1) - expf(p2) + LAMBDA_INIT_F;
}

// ---------------- GEMM: C(f32) = A(bf16, MxK) @ Bt(bf16, NxK)^T ----------------
// 128x128 tile, BK=64, 4 waves (2x2). Double-buffered stage-ahead LDS
// (attn-proven pattern): prologue-stage buf0, then per iter
// {stage(buf^1, next K); compute(buf); __syncthreads()} — one barrier/iter,
// prefetch latency hides under the 128 MFMAs. Chunk-XOR swizzle (0-conflict,
// verified R7): linear gload_lds dest + inverse-swizzled source + XOR reads.
__global__ __launch_bounds__(256) void gemm_bt_kernel(
    const u16* __restrict__ A, const u16* __restrict__ Bt,
    float* __restrict__ C, int M, int N, int K) {
  __shared__ u16 As[2][128 * 64];
  __shared__ u16 Bs[2][128 * 64];
  const int tid = threadIdx.x;
  const int lane = tid & 63;
  const int w = tid >> 6;
  const int wm = w >> 1, wn = w & 1;
  const long m0 = (long)blockIdx.y * 128;
  const long n0 = (long)blockIdx.x * 128;

  f32x4 acc[4][4];
#pragma unroll
  for (int i = 0; i < 4; ++i)
#pragma unroll
    for (int j = 0; j < 4; ++j) acc[i][j] = f32x4{0.f, 0.f, 0.f, 0.f};

  const int sr = lane >> 3;                 // row within 8-row staging group
  const int scS = ((lane & 7) ^ sr) * 8;    // inverse-swizzled source col (elems)
  const int fr = lane & 15;
  const int kgrp = lane >> 4;
  const int swz = (fr & 7) << 3;            // read-side XOR (elems)

  const u16* aSrc = A + (m0 + w * 32 + sr) * (long)K + scS;
  const u16* bSrc = Bt + (n0 + w * 32 + sr) * (long)K + scS;

  auto stage = [&](int b, long koff) {
#pragma unroll
    for (int g = 0; g < 4; ++g) {
      gload_lds16(aSrc + koff + (size_t)g * 8 * K, &As[b][(w * 32 + g * 8) * 64]);
      gload_lds16(bSrc + koff + (size_t)g * 8 * K, &Bs[b][(w * 32 + g * 8) * 64]);
    }
  };

  stage(0, 0);
  __syncthreads();
  int cur = 0;
  for (int k0 = 0; k0 < K; k0 += 64) {
    if (k0 + 64 < K) stage(cur ^ 1, k0 + 64);  // prefetch flies during MFMA
    __builtin_amdgcn_s_setprio(1);
#pragma unroll
    for (int ks = 0; ks < 2; ++ks) {
      bf16x8 af[4], bfr[4];
#pragma unroll
      for (int mi = 0; mi < 4; ++mi)
        af[mi] = *(const bf16x8*)&As[cur][(wm * 64 + mi * 16 + fr) * 64 +
                                          ((ks * 32 + kgrp * 8) ^ swz)];
#pragma unroll
      for (int ni = 0; ni < 4; ++ni)
        bfr[ni] = *(const bf16x8*)&Bs[cur][(wn * 64 + ni * 16 + fr) * 64 +
                                           ((ks * 32 + kgrp * 8) ^ swz)];
#pragma unroll
      for (int mi = 0; mi < 4; ++mi)
#pragma unroll
        for (int ni = 0; ni < 4; ++ni)
          acc[mi][ni] =
              __builtin_amdgcn_mfma_f32_16x16x32_bf16(af[mi], bfr[ni], acc[mi][ni], 0, 0, 0);
    }
    __builtin_amdgcn_s_setprio(0);
    __syncthreads();  // drains prefetch (vmcnt0) + protects buffer swap
    cur ^= 1;
  }
  const int rg = (lane >> 4) * 4;
#pragma unroll
  for (int mi = 0; mi < 4; ++mi)
#pragma unroll
    for (int ni = 0; ni < 4; ++ni) {
      const long col = n0 + wn * 64 + ni * 16 + fr;
#pragma unroll
      for (int j = 0; j < 4; ++j) {
        const long row = m0 + wm * 64 + mi * 16 + rg + j;
        C[row * N + col] = acc[mi][ni][j];
      }
    }
}

// ---------------- RoPE apply (Q pre-scaled by 0.125*log2e) ----------------
__global__ __launch_bounds__(256) void rope_apply_kernel(
    const float* __restrict__ proj, const float* __restrict__ cosT,
    const float* __restrict__ sinT, u16* __restrict__ Qh, u16* __restrict__ Kh) {
  const int s = blockIdx.x;
  const int tid = threadIdx.x;
#pragma unroll
  for (int t = 0; t < 8; ++t) {
    const int p = t * 256 + tid;     // 0..2047
    const int isK = p >> 10;
    const int pp = p & 1023;
    const int hh = pp >> 5, i = pp & 31;
    const float* src = proj + (size_t)s * 6144 + isK * 2048 + hh * 64 + 2 * i;
    const float x1 = src[0], x2 = src[1];
    const float c = cosT[s * 32 + i], sn = sinT[s * 32 + i];
    const float scl = isK ? 1.0f : Q_PRESCALE;
    u16* dst = (isK ? Kh : Qh) + ((size_t)hh * 2048 + s) * 64 + 2 * i;
    dst[0] = f2bf((x1 * c - x2 * sn) * scl);
    dst[1] = f2bf((x1 * sn + x2 * c) * scl);
  }
}

// ------------- transpose-cast V -------------
__global__ __launch_bounds__(256) void transpose_v_kernel(const float* __restrict__ proj,
                                                          u16* __restrict__ Vt) {
  __shared__ float t[32][33];
  const int s0 = blockIdx.x * 32, r0 = blockIdx.y * 32;
  const int tx = threadIdx.x & 31, ty = threadIdx.x >> 5;
#pragma unroll
  for (int i = 0; i < 4; ++i)
    t[ty + i * 8][tx] = proj[(size_t)(s0 + ty + i * 8) * 6144 + 4096 + r0 + tx];
  __syncthreads();
#pragma unroll
  for (int i = 0; i < 4; ++i)
    Vt[(size_t)(r0 + ty + i * 8) * 2048 + s0 + tx] = f2bf(t[tx][ty + i * 8]);
}

// ---------------- flash attention (causal), dual streams ----------------
__global__ __launch_bounds__(256) void attn_kernel(
    const u16* __restrict__ Qh, const u16* __restrict__ Kh,
    const u16* __restrict__ Vt, float* __restrict__ attnOut) {
  __shared__ u16 Kt[2][64 * 64];   // [buf][key][d]   (chunk-swizzled)
  __shared__ u16 Vs[2][128 * 64];  // [buf][out-d][key] (chunk-swizzled)
  __shared__ __bf16 Ps[4 * 16 * 64];  // per-wave P staging (swizzled)
  const int tid = threadIdx.x, lane = tid & 63, w = tid >> 6;
  const int fr = lane & 15, kgrp = lane >> 4;
  const int bid = blockIdx.x;
  const int xcd = bid & 7, idx = bid >> 3;
  const int hh = xcd * 4 + (idx & 3);     // 4 head-streams per XCD group
  const int pairIdx = idx >> 2;           // 0..15
  const int h = hh >> 1, comp = hh & 1;
  const int q0A = pairIdx * 64, q0B = (31 - pairIdx) * 64;
  const int jmaxA = pairIdx, jmaxB = 31 - pairIdx;
  const int ntA = jmaxA + 1, ntot = ntA + jmaxB + 1;  // == 33

  const int sr = lane >> 3;
  const int scS = (((lane & 7) ^ sr) * 8);  // source-swizzled column (elems)
  const int swz = (fr & 7) << 3;            // read-side XOR (elems)

  bf16x8 qf0, qf1;
  {
    const u16* qb = Qh + ((size_t)hh * 2048 + q0A + w * 16 + fr) * 64 + kgrp * 8;
    qf0 = *(const bf16x8*)qb;
    qf1 = *(const bf16x8*)(qb + 32);
  }
  bf16x8 onesf;
#pragma unroll
  for (int i = 0; i < 8; ++i) onesf[i] = (__bf16)1.0f;

  // o[0..7] = output d-frags; o[8] = row-sum accumulator (ones-MFMA)
  f32x4 o[9];
#pragma unroll
  for (int i = 0; i < 9; ++i) o[i] = f32x4{0.f, 0.f, 0.f, 0.f};
  float m_r[4] = {-1e30f, -1e30f, -1e30f, -1e30f};

  auto stage = [&](int b, int kv0) {
#pragma unroll
    for (int i = 0; i < 2; ++i)
      gload_lds16(Kh + ((size_t)hh * 2048 + kv0 + i * 32 + w * 8 + sr) * 64 + scS,
                  &Kt[b][(i * 32 + w * 8) * 64]);
#pragma unroll
    for (int i = 0; i < 4; ++i)
      gload_lds16(Vt + ((size_t)h * 128 + i * 32 + w * 8 + sr) * 2048 + kv0 + scS,
                  &Vs[b][(i * 32 + w * 8) * 64]);
  };

  auto writeOut = [&](int q0) {
    float* outp = attnOut + (size_t)comp * (2048 * 2048);
#pragma unroll
    for (int j = 0; j < 4; ++j) {
      const int row = q0 + w * 16 + kgrp * 4 + j;
      const float inv = 1.0f / o[8][j];
      float* op = outp + (size_t)row * 2048 + h * 128;
#pragma unroll
      for (int nf = 0; nf < 8; ++nf) op[nf * 16 + fr] = o[nf][j] * inv;
    }
  };

  stage(0, 0);
  __syncthreads();

  for (int t = 0; t < ntot; ++t) {
    const int cur = t & 1;
    if (t + 1 < ntot) {
      const int nk = (t + 1 < ntA) ? (t + 1) * 64 : (t + 1 - ntA) * 64;
      stage(cur ^ 1, nk);
    }
    const bool inA = t < ntA;
    const int q0 = inA ? q0A : q0B;
    const int jj = inA ? t : t - ntA;
    const int kv0 = jj * 64;
    const bool diag = inA ? (jj == jmaxA) : (jj == jmaxB);

    // ---- QK^T (scores already scaled, exp2 domain) ----
    f32x4 s[4];
    __builtin_amdgcn_s_setprio(1);
#pragma unroll
    for (int nf = 0; nf < 4; ++nf) {
      s[nf] = f32x4{0.f, 0.f, 0.f, 0.f};
      const bf16x8 b0 = *(const bf16x8*)&Kt[cur][(nf * 16 + fr) * 64 + ((kgrp * 8) ^ swz)];
      const bf16x8 b1 =
          *(const bf16x8*)&Kt[cur][(nf * 16 + fr) * 64 + ((32 + kgrp * 8) ^ swz)];
      s[nf] = __builtin_amdgcn_mfma_f32_16x16x32_bf16(qf0, b0, s[nf], 0, 0, 0);
      s[nf] = __builtin_amdgcn_mfma_f32_16x16x32_bf16(qf1, b1, s[nf], 0, 0, 0);
    }
    __builtin_amdgcn_s_setprio(0);

    // ---- mask + row max ----
    float pmax[4] = {-1e30f, -1e30f, -1e30f, -1e30f};
    if (diag) {
#pragma unroll
      for (int nf = 0; nf < 4; ++nf) {
        const int key = kv0 + nf * 16 + fr;
#pragma unroll
        for (int j = 0; j < 4; ++j) {
          float sc2 = s[nf][j];
          if (key > q0 + w * 16 + kgrp * 4 + j) sc2 = -1e30f;
          s[nf][j] = sc2;
          pmax[j] = fmaxf(pmax[j], sc2);
        }
      }
    } else {
#pragma unroll
      for (int nf = 0; nf < 4; ++nf)
#pragma unroll
        for (int j = 0; j < 4; ++j) pmax[j] = fmaxf(pmax[j], s[nf][j]);
    }
#pragma unroll
    for (int j = 0; j < 4; ++j)
#pragma unroll
      for (int mk = 1; mk < 16; mk <<= 1) pmax[j] = fmaxf(pmax[j], __shfl_xor(pmax[j], mk));

    // ---- defer-rescale (exact: only when a row max grew) ----
    bool grow = false;
#pragma unroll
    for (int j = 0; j < 4; ++j) grow |= (pmax[j] > m_r[j]);
    if (__any(grow)) {
#pragma unroll
      for (int j = 0; j < 4; ++j) {
        const float mn = fmaxf(m_r[j], pmax[j]);
        const float sf = fast_exp2(m_r[j] - mn);
        m_r[j] = mn;
#pragma unroll
        for (int nf = 0; nf < 9; ++nf) o[nf][j] *= sf;
      }
    }

    // ---- exp2 + P staging (swizzled, native bf16 cast) ----
#pragma unroll
    for (int nf = 0; nf < 4; ++nf)
#pragma unroll
      for (int j = 0; j < 4; ++j) {
        const float p = fast_exp2(s[nf][j] - m_r[j]);
        const int prow = kgrp * 4 + j;
        Ps[w * 1024 + prow * 64 + ((nf * 16 + fr) ^ ((prow & 7) << 3))] = (__bf16)p;
      }

    // ---- PV (+ ones-MFMA row-sum into o[8]) ----
    const bf16x8 pa0 = *(const bf16x8*)&Ps[w * 1024 + fr * 64 + ((kgrp * 8) ^ swz)];
    const bf16x8 pa1 = *(const bf16x8*)&Ps[w * 1024 + fr * 64 + ((32 + kgrp * 8) ^ swz)];
    __builtin_amdgcn_s_setprio(1);
#pragma unroll
    for (int nf = 0; nf < 8; ++nf) {
      const bf16x8 v0 = *(const bf16x8*)&Vs[cur][(nf * 16 + fr) * 64 + ((kgrp * 8) ^ swz)];
      const bf16x8 v1 =
          *(const bf16x8*)&Vs[cur][(nf * 16 + fr) * 64 + ((32 + kgrp * 8) ^ swz)];
      o[nf] = __builtin_amdgcn_mfma_f32_16x16x32_bf16(pa0, v0, o[nf], 0, 0, 0);
      o[nf] = __builtin_amdgcn_mfma_f32_16x16x32_bf16(pa1, v1, o[nf], 0, 0, 0);
    }
    o[8] = __builtin_amdgcn_mfma_f32_16x16x32_bf16(pa0, onesf, o[8], 0, 0, 0);
    o[8] = __builtin_amdgcn_mfma_f32_16x16x32_bf16(pa1, onesf, o[8], 0, 0, 0);
    __builtin_amdgcn_s_setprio(0);

    // ---- sub-problem switch: flush A, reset state, load B's Q ----
    if (t == jmaxA) {
      writeOut(q0A);
#pragma unroll
      for (int i = 0; i < 9; ++i) o[i] = f32x4{0.f, 0.f, 0.f, 0.f};
#pragma unroll
      for (int j = 0; j < 4; ++j) m_r[j] = -1e30f;
      const u16* qb = Qh + ((size_t)hh * 2048 + q0B + w * 16 + fr) * 64 + kgrp * 8;
      qf0 = *(const bf16x8*)qb;
      qf1 = *(const bf16x8*)(qb + 32);
    }
    __syncthreads();
  }
  writeOut(q0B);
}

// ---------------- combine ----------------
__global__ __launch_bounds__(256) void combine_kernel(
    const float* __restrict__ attn, const float* __restrict__ lam,
    const float* __restrict__ g, u16* __restrict__ ab) {
  const int lane = threadIdx.x & 63;
  const int idx = blockIdx.x * 4 + (threadIdx.x >> 6);  // (s,h)
  const int s = idx >> 4, h = idx & 15;
  const float lf = *lam;
  const float* a1 = attn + (size_t)s * 2048 + h * 128;
  const float* a2 = a1 + (size_t)2048 * 2048;
  const float x0 = a1[lane] - lf * a2[lane];
  const float x1 = a1[lane + 64] - lf * a2[lane + 64];
  float ss = x0 * x0 + x1 * x1;
#pragma unroll
  for (int mk = 1; mk < 64; mk <<= 1) ss += __shfl_xor(ss, mk);
  const float r = rsqrtf(ss * (1.0f / 128.0f) + 1e-5f) * ONE_MINUS_LI;
  u16* op = ab + (size_t)s * 2048 + h * 128;
  op[lane] = f2bf(x0 * r * g[lane]);
  op[lane + 64] = f2bf(x1 * r * g[lane + 64]);
}

extern "C" void kernel_launch(void* const* d_in, const int* in_sizes, int n_in,
                              void* d_out, int out_size, void* d_ws, size_t ws_size,
                              hipStream_t stream) {
  const float* x = (const float*)d_in[0];
  const float* Wq = (const float*)d_in[1];
  const float* Wk = (const float*)d_in[2];
  const float* Wv = (const float*)d_in[3];
  const float* Wo = (const float*)d_in[4];
  const float* lq1 = (const float*)d_in[5];
  const float* lk1 = (const float*)d_in[6];
  const float* lq2 = (const float*)d_in[7];
  const float* lk2 = (const float*)d_in[8];
  const float* g = (const float*)d_in[9];
  float* out = (float*)d_out;

  char* ws = (char*)d_ws;
  u16* xb = (u16*)(ws);                                 // 8 MiB
  u16* WqkvT = (u16*)(ws + (size_t)(8u << 20));         // 24 MiB
  u16* WoT = (u16*)(ws + (size_t)(32u << 20));          // 8 MiB
  float* proj = (float*)(ws + (size_t)(40u << 20));     // 48 MiB (reused as attn)
  float* attn = proj;                                   // 32 MiB (attn1|attn2)
  u16* Qh = (u16*)(ws + (size_t)(88u << 20));           // 8 MiB
  u16* Kh = (u16*)(ws + (size_t)(96u << 20));           // 8 MiB
  u16* Vt = (u16*)(ws + (size_t)(104u << 20));          // 8 MiB
  u16* ab = (u16*)(ws + (size_t)(112u << 20));          // 8 MiB
  float* cosT = (float*)(ws + (size_t)(120u << 20));    // 256 KiB
  float* sinT = (float*)(ws + (size_t)(120u << 20) + (256u << 10));
  float* lam = (float*)(ws + (size_t)(120u << 20) + (512u << 10));

  cast_x_kernel<<<4096, 256, 0, stream>>>(x, xb);
  transpose_w_kernel<<<dim3(64, 64, 4), 256, 0, stream>>>(Wq, Wk, Wv, Wo, WqkvT, WoT);
  rope_table_kernel<<<256, 256, 0, stream>>>(cosT, sinT);
  lambda_kernel<<<1, 64, 0, stream>>>(lq1, lk1, lq2, lk2, lam);
  gemm_bt_kernel<<<dim3(48, 16), 256, 0, stream>>>(xb, WqkvT, proj, 2048, 6144, 2048);
  rope_apply_kernel<<<2048, 256, 0, stream>>>(proj, cosT, sinT, Qh, Kh);
  transpose_v_kernel<<<dim3(64, 64), 256, 0, stream>>>(proj, Vt);
  attn_kernel<<<512, 256, 0, stream>>>(Qh, Kh, Vt, attn);
  combine_kernel<<<8192, 256, 0, stream>>>(attn, lam, g, ab);
  gemm_bt_kernel<<<dim3(16, 16), 256, 0, stream>>>(ab, WoT, out, 2048, 2048, 2048);
}

// Round 9
// 315.964 us; speedup vs baseline: 1.1050x; 1.0723x over previous
//
#include <hip/hip_runtime.h>

typedef unsigned short u16;
typedef __bf16 bf16x8 __attribute__((ext_vector_type(8)));
typedef float f32x4 __attribute__((ext_vector_type(4)));

#define LAMBDA_INIT_F 0.7836057665f
#define ONE_MINUS_LI  0.2163942335f
// 0.125 * log2(e): folds the 1/sqrt(64) score scale AND the exp->exp2
// conversion into the Q values (bf16 relative precision unaffected).
#define Q_PRESCALE 0.1803368801f

__device__ __forceinline__ u16 f2bf(float f) {
  union { float f; unsigned u; } v; v.f = f;
  unsigned r = v.u + 0x7fffu + ((v.u >> 16) & 1u);
  return (u16)(r >> 16);
}

__device__ __forceinline__ float fast_exp2(float x) {
#if __has_builtin(__builtin_amdgcn_exp2f)
  return __builtin_amdgcn_exp2f(x);   // v_exp_f32: hardware exp2
#else
  return __builtin_exp2f(x);
#endif
}

__device__ __forceinline__ void gload_lds16(const void* g, void* l) {
  __builtin_amdgcn_global_load_lds(
      (const __attribute__((address_space(1))) void*)g,
      (__attribute__((address_space(3))) void*)l, 16, 0, 0);
}

// ---------------- fused prep: transpose_w | cast_x | rope_table | lambda ----------------
// grid.x = 16384 (transpose_w) + 4096 (cast_x) + 256 (rope_table) + 1 (lambda)
__global__ __launch_bounds__(256) void prep_kernel(
    const float* __restrict__ x, const float* __restrict__ Wq,
    const float* __restrict__ Wk, const float* __restrict__ Wv,
    const float* __restrict__ Wo, const float* __restrict__ lq1,
    const float* __restrict__ lk1, const float* __restrict__ lq2,
    const float* __restrict__ lk2, u16* __restrict__ xb,
    u16* __restrict__ WqkvT, u16* __restrict__ WoT,
    float* __restrict__ cosT, float* __restrict__ sinT, float* __restrict__ lam) {
  __shared__ float t[32][33];
  const int bid = blockIdx.x;
  const int tid = threadIdx.x;
  if (bid < 16384) {
    // ---- transpose-cast weights ----
    const int z = bid >> 12;
    const int rem = bid & 4095;
    const int n0 = (rem & 63) * 32, k0 = (rem >> 6) * 32;
    const float* src = (z == 0) ? Wq : (z == 1) ? Wk : (z == 2) ? Wv : Wo;
    const int tx = tid & 31, ty = tid >> 5;
#pragma unroll
    for (int i = 0; i < 4; ++i)
      t[ty + i * 8][tx] = src[(size_t)(k0 + ty + i * 8) * 2048 + n0 + tx];
    __syncthreads();
    u16* dst = (z < 3) ? (WqkvT + ((size_t)z * 2048 + n0) * 2048 + k0)
                       : (WoT + (size_t)n0 * 2048 + k0);
#pragma unroll
    for (int i = 0; i < 4; ++i)
      dst[(size_t)(ty + i * 8) * 2048 + tx] = f2bf(t[tx][ty + i * 8]);
  } else if (bid < 16384 + 4096) {
    // ---- cast x -> bf16 ----
    const int i = ((bid - 16384) * 256 + tid) * 4;
    const float4 v = *(const float4*)(x + i);
    u16 tmp[4] = {f2bf(v.x), f2bf(v.y), f2bf(v.z), f2bf(v.w)};
    *(uint2*)(xb + i) = *(const uint2*)tmp;
  } else if (bid < 16384 + 4096 + 256) {
    // ---- RoPE tables ----
    const int idx = (bid - 16384 - 4096) * 256 + tid;  // S*32 = 65536
    const int s = idx >> 5, i = idx & 31;
    const float div = expf((float)(2 * i) * (-9.210340371976184f / 64.f));
    const float ang = (float)s * div;
    cosT[idx] = cosf(ang);
    sinT[idx] = sinf(ang);
  } else {
    // ---- lambda ----
    if (tid < 64) {
      float p1 = lq1[tid] * lk1[tid];
      float p2 = lq2[tid] * lk2[tid];
#pragma unroll
      for (int mk = 1; mk < 64; mk <<= 1) {
        p1 += __shfl_xor(p1, mk);
        p2 += __shfl_xor(p2, mk);
      }
      if (tid == 0) *lam = expf(p1) - expf(p2) + LAMBDA_INIT_F;
    }
  }
}

// ---------------- GEMM: C = A(bf16, MxK) @ Bt(bf16, NxK)^T ----------------
// 128x128 tile, BK=64, 4 waves (2x2), double-buffered stage-ahead LDS,
// chunk-XOR swizzle (0-conflict, verified). mode 0: plain fp32 C write.
// mode 1 (QKV): fused epilogue — RoPE (shfl pair) -> Qh/Kh bf16 (Q
// pre-scaled), V transposed -> Vt bf16; proj is never materialized.
__global__ __launch_bounds__(256) void gemm_bt_kernel(
    const u16* __restrict__ A, const u16* __restrict__ Bt,
    float* __restrict__ C, int M, int N, int K, int mode,
    const float* __restrict__ cosT, const float* __restrict__ sinT,
    u16* __restrict__ Qh, u16* __restrict__ Kh, u16* __restrict__ Vt) {
  __shared__ u16 As[2][128 * 64];
  __shared__ u16 Bs[2][128 * 64];
  const int tid = threadIdx.x;
  const int lane = tid & 63;
  const int w = tid >> 6;
  const int wm = w >> 1, wn = w & 1;
  const long m0 = (long)blockIdx.y * 128;
  const long n0 = (long)blockIdx.x * 128;

  f32x4 acc[4][4];
#pragma unroll
  for (int i = 0; i < 4; ++i)
#pragma unroll
    for (int j = 0; j < 4; ++j) acc[i][j] = f32x4{0.f, 0.f, 0.f, 0.f};

  const int sr = lane >> 3;                 // row within 8-row staging group
  const int scS = ((lane & 7) ^ sr) * 8;    // inverse-swizzled source col (elems)
  const int fr = lane & 15;
  const int kgrp = lane >> 4;
  const int swz = (fr & 7) << 3;            // read-side XOR (elems)

  const u16* aSrc = A + (m0 + w * 32 + sr) * (long)K + scS;
  const u16* bSrc = Bt + (n0 + w * 32 + sr) * (long)K + scS;

  auto stage = [&](int b, long koff) {
#pragma unroll
    for (int g = 0; g < 4; ++g) {
      gload_lds16(aSrc + koff + (size_t)g * 8 * K, &As[b][(w * 32 + g * 8) * 64]);
      gload_lds16(bSrc + koff + (size_t)g * 8 * K, &Bs[b][(w * 32 + g * 8) * 64]);
    }
  };

  stage(0, 0);
  __syncthreads();
  int cur = 0;
  for (int k0 = 0; k0 < K; k0 += 64) {
    if (k0 + 64 < K) stage(cur ^ 1, k0 + 64);  // prefetch flies during MFMA
    __builtin_amdgcn_s_setprio(1);
#pragma unroll
    for (int ks = 0; ks < 2; ++ks) {
      bf16x8 af[4], bfr[4];
#pragma unroll
      for (int mi = 0; mi < 4; ++mi)
        af[mi] = *(const bf16x8*)&As[cur][(wm * 64 + mi * 16 + fr) * 64 +
                                          ((ks * 32 + kgrp * 8) ^ swz)];
#pragma unroll
      for (int ni = 0; ni < 4; ++ni)
        bfr[ni] = *(const bf16x8*)&Bs[cur][(wn * 64 + ni * 16 + fr) * 64 +
                                           ((ks * 32 + kgrp * 8) ^ swz)];
#pragma unroll
      for (int mi = 0; mi < 4; ++mi)
#pragma unroll
        for (int ni = 0; ni < 4; ++ni)
          acc[mi][ni] =
              __builtin_amdgcn_mfma_f32_16x16x32_bf16(af[mi], bfr[ni], acc[mi][ni], 0, 0, 0);
    }
    __builtin_amdgcn_s_setprio(0);
    __syncthreads();  // drains prefetch (vmcnt0) + protects buffer swap
    cur ^= 1;
  }
  const int rg = (lane >> 4) * 4;
  if (mode == 0) {
#pragma unroll
    for (int mi = 0; mi < 4; ++mi)
#pragma unroll
      for (int ni = 0; ni < 4; ++ni) {
        const long col = n0 + wn * 64 + ni * 16 + fr;
#pragma unroll
        for (int j = 0; j < 4; ++j) {
          const long row = m0 + wm * 64 + mi * 16 + rg + j;
          C[row * N + col] = acc[mi][ni][j];
        }
      }
  } else if (n0 >= 4096) {
    // ---- V epilogue: Vt[(col-4096)*2048 + row] = bf16(acc) ----
#pragma unroll
    for (int mi = 0; mi < 4; ++mi)
#pragma unroll
      for (int ni = 0; ni < 4; ++ni) {
        const long vr = n0 - 4096 + wn * 64 + ni * 16 + fr;
#pragma unroll
        for (int j = 0; j < 4; ++j) {
          const long row = m0 + wm * 64 + mi * 16 + rg + j;
          Vt[vr * 2048 + row] = f2bf(acc[mi][ni][j]);
        }
      }
  } else {
    // ---- Q/K epilogue: in-register RoPE via lane-pair shfl ----
    const int isK = (int)(n0 >> 11);
    u16* dstBase = isK ? Kh : Qh;
    const float scl = isK ? 1.0f : Q_PRESCALE;
#pragma unroll
    for (int mi = 0; mi < 4; ++mi)
#pragma unroll
      for (int ni = 0; ni < 4; ++ni) {
        const int col = (int)(n0 & 2047) + wn * 64 + ni * 16 + fr;
        const int hh = col >> 6, d = col & 63, i2 = (col & 63) >> 1;
        const bool odd = d & 1;
#pragma unroll
        for (int j = 0; j < 4; ++j) {
          const int row = (int)m0 + wm * 64 + mi * 16 + rg + j;
          const float v = acc[mi][ni][j];
          const float p = __shfl_xor(v, 1);   // pair partner (col^1, same row)
          const float c = cosT[row * 32 + i2], sn = sinT[row * 32 + i2];
          const float outv = odd ? (p * sn + v * c) : (v * c - p * sn);
          dstBase[((size_t)hh * 2048 + row) * 64 + d] = f2bf(outv * scl);
        }
      }
  }
}

// ---------------- flash attention (causal), dual streams ----------------
__global__ __launch_bounds__(256) void attn_kernel(
    const u16* __restrict__ Qh, const u16* __restrict__ Kh,
    const u16* __restrict__ Vt, float* __restrict__ attnOut) {
  __shared__ u16 Kt[2][64 * 64];   // [buf][key][d]   (chunk-swizzled)
  __shared__ u16 Vs[2][128 * 64];  // [buf][out-d][key] (chunk-swizzled)
  __shared__ __bf16 Ps[4 * 16 * 64];  // per-wave P staging (swizzled)
  const int tid = threadIdx.x, lane = tid & 63, w = tid >> 6;
  const int fr = lane & 15, kgrp = lane >> 4;
  const int bid = blockIdx.x;
  const int xcd = bid & 7, idx = bid >> 3;
  const int hh = xcd * 4 + (idx & 3);     // 4 head-streams per XCD group
  const int pairIdx = idx >> 2;           // 0..15
  const int h = hh >> 1, comp = hh & 1;
  const int q0A = pairIdx * 64, q0B = (31 - pairIdx) * 64;
  const int jmaxA = pairIdx, jmaxB = 31 - pairIdx;
  const int ntA = jmaxA + 1, ntot = ntA + jmaxB + 1;  // == 33

  const int sr = lane >> 3;
  const int scS = (((lane & 7) ^ sr) * 8);  // source-swizzled column (elems)
  const int swz = (fr & 7) << 3;            // read-side XOR (elems)

  bf16x8 qf0, qf1;
  {
    const u16* qb = Qh + ((size_t)hh * 2048 + q0A + w * 16 + fr) * 64 + kgrp * 8;
    qf0 = *(const bf16x8*)qb;
    qf1 = *(const bf16x8*)(qb + 32);
  }
  bf16x8 onesf;
#pragma unroll
  for (int i = 0; i < 8; ++i) onesf[i] = (__bf16)1.0f;

  // o[0..7] = output d-frags; o[8] = row-sum accumulator (ones-MFMA)
  f32x4 o[9];
#pragma unroll
  for (int i = 0; i < 9; ++i) o[i] = f32x4{0.f, 0.f, 0.f, 0.f};
  float m_r[4] = {-1e30f, -1e30f, -1e30f, -1e30f};

  auto stage = [&](int b, int kv0) {
#pragma unroll
    for (int i = 0; i < 2; ++i)
      gload_lds16(Kh + ((size_t)hh * 2048 + kv0 + i * 32 + w * 8 + sr) * 64 + scS,
                  &Kt[b][(i * 32 + w * 8) * 64]);
#pragma unroll
    for (int i = 0; i < 4; ++i)
      gload_lds16(Vt + ((size_t)h * 128 + i * 32 + w * 8 + sr) * 2048 + kv0 + scS,
                  &Vs[b][(i * 32 + w * 8) * 64]);
  };

  auto writeOut = [&](int q0) {
    float* outp = attnOut + (size_t)comp * (2048 * 2048);
#pragma unroll
    for (int j = 0; j < 4; ++j) {
      const int row = q0 + w * 16 + kgrp * 4 + j;
      const float inv = 1.0f / o[8][j];
      float* op = outp + (size_t)row * 2048 + h * 128;
#pragma unroll
      for (int nf = 0; nf < 8; ++nf) op[nf * 16 + fr] = o[nf][j] * inv;
    }
  };

  stage(0, 0);
  __syncthreads();

  for (int t = 0; t < ntot; ++t) {
    const int cur = t & 1;
    if (t + 1 < ntot) {
      const int nk = (t + 1 < ntA) ? (t + 1) * 64 : (t + 1 - ntA) * 64;
      stage(cur ^ 1, nk);
    }
    const bool inA = t < ntA;
    const int q0 = inA ? q0A : q0B;
    const int jj = inA ? t : t - ntA;
    const int kv0 = jj * 64;
    const bool diag = inA ? (jj == jmaxA) : (jj == jmaxB);

    // ---- QK^T (scores already scaled, exp2 domain) ----
    f32x4 s[4];
    __builtin_amdgcn_s_setprio(1);
#pragma unroll
    for (int nf = 0; nf < 4; ++nf) {
      s[nf] = f32x4{0.f, 0.f, 0.f, 0.f};
      const bf16x8 b0 = *(const bf16x8*)&Kt[cur][(nf * 16 + fr) * 64 + ((kgrp * 8) ^ swz)];
      const bf16x8 b1 =
          *(const bf16x8*)&Kt[cur][(nf * 16 + fr) * 64 + ((32 + kgrp * 8) ^ swz)];
      s[nf] = __builtin_amdgcn_mfma_f32_16x16x32_bf16(qf0, b0, s[nf], 0, 0, 0);
      s[nf] = __builtin_amdgcn_mfma_f32_16x16x32_bf16(qf1, b1, s[nf], 0, 0, 0);
    }
    __builtin_amdgcn_s_setprio(0);

    // ---- mask + row max ----
    float pmax[4] = {-1e30f, -1e30f, -1e30f, -1e30f};
    if (diag) {
#pragma unroll
      for (int nf = 0; nf < 4; ++nf) {
        const int key = kv0 + nf * 16 + fr;
#pragma unroll
        for (int j = 0; j < 4; ++j) {
          float sc2 = s[nf][j];
          if (key > q0 + w * 16 + kgrp * 4 + j) sc2 = -1e30f;
          s[nf][j] = sc2;
          pmax[j] = fmaxf(pmax[j], sc2);
        }
      }
    } else {
#pragma unroll
      for (int nf = 0; nf < 4; ++nf)
#pragma unroll
        for (int j = 0; j < 4; ++j) pmax[j] = fmaxf(pmax[j], s[nf][j]);
    }
#pragma unroll
    for (int j = 0; j < 4; ++j)
#pragma unroll
      for (int mk = 1; mk < 16; mk <<= 1) pmax[j] = fmaxf(pmax[j], __shfl_xor(pmax[j], mk));

    // ---- defer-rescale (exact: only when a row max grew) ----
    bool grow = false;
#pragma unroll
    for (int j = 0; j < 4; ++j) grow |= (pmax[j] > m_r[j]);
    if (__any(grow)) {
#pragma unroll
      for (int j = 0; j < 4; ++j) {
        const float mn = fmaxf(m_r[j], pmax[j]);
        const float sf = fast_exp2(m_r[j] - mn);
        m_r[j] = mn;
#pragma unroll
        for (int nf = 0; nf < 9; ++nf) o[nf][j] *= sf;
      }
    }

    // ---- exp2 + P staging (swizzled, native bf16 cast) ----
#pragma unroll
    for (int nf = 0; nf < 4; ++nf)
#pragma unroll
      for (int j = 0; j < 4; ++j) {
        const float p = fast_exp2(s[nf][j] - m_r[j]);
        const int prow = kgrp * 4 + j;
        Ps[w * 1024 + prow * 64 + ((nf * 16 + fr) ^ ((prow & 7) << 3))] = (__bf16)p;
      }

    // ---- PV (+ ones-MFMA row-sum into o[8]) ----
    const bf16x8 pa0 = *(const bf16x8*)&Ps[w * 1024 + fr * 64 + ((kgrp * 8) ^ swz)];
    const bf16x8 pa1 = *(const bf16x8*)&Ps[w * 1024 + fr * 64 + ((32 + kgrp * 8) ^ swz)];
    __builtin_amdgcn_s_setprio(1);
#pragma unroll
    for (int nf = 0; nf < 8; ++nf) {
      const bf16x8 v0 = *(const bf16x8*)&Vs[cur][(nf * 16 + fr) * 64 + ((kgrp * 8) ^ swz)];
      const bf16x8 v1 =
          *(const bf16x8*)&Vs[cur][(nf * 16 + fr) * 64 + ((32 + kgrp * 8) ^ swz)];
      o[nf] = __builtin_amdgcn_mfma_f32_16x16x32_bf16(pa0, v0, o[nf], 0, 0, 0);
      o[nf] = __builtin_amdgcn_mfma_f32_16x16x32_bf16(pa1, v1, o[nf], 0, 0, 0);
    }
    o[8] = __builtin_amdgcn_mfma_f32_16x16x32_bf16(pa0, onesf, o[8], 0, 0, 0);
    o[8] = __builtin_amdgcn_mfma_f32_16x16x32_bf16(pa1, onesf, o[8], 0, 0, 0);
    __builtin_amdgcn_s_setprio(0);

    // ---- sub-problem switch: flush A, reset state, load B's Q ----
    if (t == jmaxA) {
      writeOut(q0A);
#pragma unroll
      for (int i = 0; i < 9; ++i) o[i] = f32x4{0.f, 0.f, 0.f, 0.f};
#pragma unroll
      for (int j = 0; j < 4; ++j) m_r[j] = -1e30f;
      const u16* qb = Qh + ((size_t)hh * 2048 + q0B + w * 16 + fr) * 64 + kgrp * 8;
      qf0 = *(const bf16x8*)qb;
      qf1 = *(const bf16x8*)(qb + 32);
    }
    __syncthreads();
  }
  writeOut(q0B);
}

// ---------------- combine ----------------
__global__ __launch_bounds__(256) void combine_kernel(
    const float* __restrict__ attn, const float* __restrict__ lam,
    const float* __restrict__ g, u16* __restrict__ ab) {
  const int lane = threadIdx.x & 63;
  const int idx = blockIdx.x * 4 + (threadIdx.x >> 6);  // (s,h)
  const int s = idx >> 4, h = idx & 15;
  const float lf = *lam;
  const float* a1 = attn + (size_t)s * 2048 + h * 128;
  const float* a2 = a1 + (size_t)2048 * 2048;
  const float x0 = a1[lane] - lf * a2[lane];
  const float x1 = a1[lane + 64] - lf * a2[lane + 64];
  float ss = x0 * x0 + x1 * x1;
#pragma unroll
  for (int mk = 1; mk < 64; mk <<= 1) ss += __shfl_xor(ss, mk);
  const float r = rsqrtf(ss * (1.0f / 128.0f) + 1e-5f) * ONE_MINUS_LI;
  u16* op = ab + (size_t)s * 2048 + h * 128;
  op[lane] = f2bf(x0 * r * g[lane]);
  op[lane + 64] = f2bf(x1 * r * g[lane + 64]);
}

extern "C" void kernel_launch(void* const* d_in, const int* in_sizes, int n_in,
                              void* d_out, int out_size, void* d_ws, size_t ws_size,
                              hipStream_t stream) {
  const float* x = (const float*)d_in[0];
  const float* Wq = (const float*)d_in[1];
  const float* Wk = (const float*)d_in[2];
  const float* Wv = (const float*)d_in[3];
  const float* Wo = (const float*)d_in[4];
  const float* lq1 = (const float*)d_in[5];
  const float* lk1 = (const float*)d_in[6];
  const float* lq2 = (const float*)d_in[7];
  const float* lk2 = (const float*)d_in[8];
  const float* g = (const float*)d_in[9];
  float* out = (float*)d_out;

  char* ws = (char*)d_ws;
  u16* xb = (u16*)(ws);                                 // 8 MiB
  u16* WqkvT = (u16*)(ws + (size_t)(8u << 20));         // 24 MiB
  u16* WoT = (u16*)(ws + (size_t)(32u << 20));          // 8 MiB
  float* attn = (float*)(ws + (size_t)(40u << 20));     // 32 MiB (attn1|attn2)
  u16* Qh = (u16*)(ws + (size_t)(88u << 20));           // 8 MiB
  u16* Kh = (u16*)(ws + (size_t)(96u << 20));           // 8 MiB
  u16* Vt = (u16*)(ws + (size_t)(104u << 20));          // 8 MiB
  u16* ab = (u16*)(ws + (size_t)(112u << 20));          // 8 MiB
  float* cosT = (float*)(ws + (size_t)(120u << 20));    // 256 KiB
  float* sinT = (float*)(ws + (size_t)(120u << 20) + (256u << 10));
  float* lam = (float*)(ws + (size_t)(120u << 20) + (512u << 10));

  prep_kernel<<<16384 + 4096 + 256 + 1, 256, 0, stream>>>(
      x, Wq, Wk, Wv, Wo, lq1, lk1, lq2, lk2, xb, WqkvT, WoT, cosT, sinT, lam);
  gemm_bt_kernel<<<dim3(48, 16), 256, 0, stream>>>(xb, WqkvT, nullptr, 2048, 6144, 2048,
                                                   1, cosT, sinT, Qh, Kh, Vt);
  attn_kernel<<<512, 256, 0, stream>>>(Qh, Kh, Vt, attn);
  combine_kernel<<<8192, 256, 0, stream>>>(attn, lam, g, ab);
  gemm_bt_kernel<<<dim3(16, 16), 256, 0, stream>>>(ab, WoT, out, 2048, 2048, 2048,
                                                   0, nullptr, nullptr, nullptr, nullptr,
                                                   nullptr);
}

// Round 10
// 308.226 us; speedup vs baseline: 1.1327x; 1.0251x over previous
//
#include <hip/hip_runtime.h>

typedef unsigned short u16;
typedef __bf16 bf16x8 __attribute__((ext_vector_type(8)));
typedef float f32x4 __attribute__((ext_vector_type(4)));

#define LAMBDA_INIT_F 0.7836057665f
#define ONE_MINUS_LI  0.2163942335f
// 0.125 * log2(e): folds the 1/sqrt(64) score scale AND the exp->exp2
// conversion into the Q values (bf16 relative precision unaffected).
#define Q_PRESCALE 0.1803368801f

__device__ __forceinline__ u16 f2bf(float f) {
  union { float f; unsigned u; } v; v.f = f;
  unsigned r = v.u + 0x7fffu + ((v.u >> 16) & 1u);
  return (u16)(r >> 16);
}

__device__ __forceinline__ float fast_exp2(float x) {
#if __has_builtin(__builtin_amdgcn_exp2f)
  return __builtin_amdgcn_exp2f(x);   // v_exp_f32: hardware exp2
#else
  return __builtin_exp2f(x);
#endif
}

__device__ __forceinline__ void gload_lds16(const void* g, void* l) {
  __builtin_amdgcn_global_load_lds(
      (const __attribute__((address_space(1))) void*)g,
      (__attribute__((address_space(3))) void*)l, 16, 0, 0);
}

// ---------------- fused prep: transpose_w | cast_x | rope_table | lambda ----------------
// grid.x = 16384 (transpose_w) + 4096 (cast_x) + 256 (rope_table) + 1 (lambda)
__global__ __launch_bounds__(256) void prep_kernel(
    const float* __restrict__ x, const float* __restrict__ Wq,
    const float* __restrict__ Wk, const float* __restrict__ Wv,
    const float* __restrict__ Wo, const float* __restrict__ lq1,
    const float* __restrict__ lk1, const float* __restrict__ lq2,
    const float* __restrict__ lk2, u16* __restrict__ xb,
    u16* __restrict__ WqkvT, u16* __restrict__ WoT,
    float* __restrict__ cosT, float* __restrict__ sinT, float* __restrict__ lam) {
  __shared__ float t[32][33];
  const int bid = blockIdx.x;
  const int tid = threadIdx.x;
  if (bid < 16384) {
    // ---- transpose-cast weights ----
    const int z = bid >> 12;
    const int rem = bid & 4095;
    const int n0 = (rem & 63) * 32, k0 = (rem >> 6) * 32;
    const float* src = (z == 0) ? Wq : (z == 1) ? Wk : (z == 2) ? Wv : Wo;
    const int tx = tid & 31, ty = tid >> 5;
#pragma unroll
    for (int i = 0; i < 4; ++i)
      t[ty + i * 8][tx] = src[(size_t)(k0 + ty + i * 8) * 2048 + n0 + tx];
    __syncthreads();
    u16* dst = (z < 3) ? (WqkvT + ((size_t)z * 2048 + n0) * 2048 + k0)
                       : (WoT + (size_t)n0 * 2048 + k0);
#pragma unroll
    for (int i = 0; i < 4; ++i)
      dst[(size_t)(ty + i * 8) * 2048 + tx] = f2bf(t[tx][ty + i * 8]);
  } else if (bid < 16384 + 4096) {
    // ---- cast x -> bf16 ----
    const int i = ((bid - 16384) * 256 + tid) * 4;
    const float4 v = *(const float4*)(x + i);
    u16 tmp[4] = {f2bf(v.x), f2bf(v.y), f2bf(v.z), f2bf(v.w)};
    *(uint2*)(xb + i) = *(const uint2*)tmp;
  } else if (bid < 16384 + 4096 + 256) {
    // ---- RoPE tables ----
    const int idx = (bid - 16384 - 4096) * 256 + tid;  // S*32 = 65536
    const int s = idx >> 5, i = idx & 31;
    const float div = expf((float)(2 * i) * (-9.210340371976184f / 64.f));
    const float ang = (float)s * div;
    cosT[idx] = cosf(ang);
    sinT[idx] = sinf(ang);
  } else {
    // ---- lambda ----
    if (tid < 64) {
      float p1 = lq1[tid] * lk1[tid];
      float p2 = lq2[tid] * lk2[tid];
#pragma unroll
      for (int mk = 1; mk < 64; mk <<= 1) {
        p1 += __shfl_xor(p1, mk);
        p2 += __shfl_xor(p2, mk);
      }
      if (tid == 0) *lam = expf(p1) - expf(p2) + LAMBDA_INIT_F;
    }
  }
}

// ---------------- GEMM: C = A(bf16, MxK) @ Bt(bf16, NxK)^T ----------------
// 128x128 tile, BK=64, 4 waves (2x2), double-buffered stage-ahead LDS,
// chunk-XOR swizzle (0-conflict, verified). mode 0: plain fp32 C write.
// mode 1 (QKV): fused epilogue — RoPE (shfl pair) -> Qh/Kh bf16 (Q
// pre-scaled), V transposed -> Vt bf16; proj is never materialized.
__global__ __launch_bounds__(256) void gemm_bt_kernel(
    const u16* __restrict__ A, const u16* __restrict__ Bt,
    float* __restrict__ C, int M, int N, int K, int mode,
    const float* __restrict__ cosT, const float* __restrict__ sinT,
    u16* __restrict__ Qh, u16* __restrict__ Kh, u16* __restrict__ Vt) {
  __shared__ u16 As[2][128 * 64];
  __shared__ u16 Bs[2][128 * 64];
  const int tid = threadIdx.x;
  const int lane = tid & 63;
  const int w = tid >> 6;
  const int wm = w >> 1, wn = w & 1;
  const long m0 = (long)blockIdx.y * 128;
  const long n0 = (long)blockIdx.x * 128;

  f32x4 acc[4][4];
#pragma unroll
  for (int i = 0; i < 4; ++i)
#pragma unroll
    for (int j = 0; j < 4; ++j) acc[i][j] = f32x4{0.f, 0.f, 0.f, 0.f};

  const int sr = lane >> 3;                 // row within 8-row staging group
  const int scS = ((lane & 7) ^ sr) * 8;    // inverse-swizzled source col (elems)
  const int fr = lane & 15;
  const int kgrp = lane >> 4;
  const int swz = (fr & 7) << 3;            // read-side XOR (elems)

  const u16* aSrc = A + (m0 + w * 32 + sr) * (long)K + scS;
  const u16* bSrc = Bt + (n0 + w * 32 + sr) * (long)K + scS;

  auto stage = [&](int b, long koff) {
#pragma unroll
    for (int g = 0; g < 4; ++g) {
      gload_lds16(aSrc + koff + (size_t)g * 8 * K, &As[b][(w * 32 + g * 8) * 64]);
      gload_lds16(bSrc + koff + (size_t)g * 8 * K, &Bs[b][(w * 32 + g * 8) * 64]);
    }
  };

  stage(0, 0);
  __syncthreads();
  int cur = 0;
  for (int k0 = 0; k0 < K; k0 += 64) {
    if (k0 + 64 < K) stage(cur ^ 1, k0 + 64);  // prefetch flies during MFMA
    __builtin_amdgcn_s_setprio(1);
#pragma unroll
    for (int ks = 0; ks < 2; ++ks) {
      bf16x8 af[4], bfr[4];
#pragma unroll
      for (int mi = 0; mi < 4; ++mi)
        af[mi] = *(const bf16x8*)&As[cur][(wm * 64 + mi * 16 + fr) * 64 +
                                          ((ks * 32 + kgrp * 8) ^ swz)];
#pragma unroll
      for (int ni = 0; ni < 4; ++ni)
        bfr[ni] = *(const bf16x8*)&Bs[cur][(wn * 64 + ni * 16 + fr) * 64 +
                                           ((ks * 32 + kgrp * 8) ^ swz)];
#pragma unroll
      for (int mi = 0; mi < 4; ++mi)
#pragma unroll
        for (int ni = 0; ni < 4; ++ni)
          acc[mi][ni] =
              __builtin_amdgcn_mfma_f32_16x16x32_bf16(af[mi], bfr[ni], acc[mi][ni], 0, 0, 0);
    }
    __builtin_amdgcn_s_setprio(0);
    __syncthreads();  // drains prefetch (vmcnt0) + protects buffer swap
    cur ^= 1;
  }
  const int rg = (lane >> 4) * 4;
  if (mode == 0) {
#pragma unroll
    for (int mi = 0; mi < 4; ++mi)
#pragma unroll
      for (int ni = 0; ni < 4; ++ni) {
        const long col = n0 + wn * 64 + ni * 16 + fr;
#pragma unroll
        for (int j = 0; j < 4; ++j) {
          const long row = m0 + wm * 64 + mi * 16 + rg + j;
          C[row * N + col] = acc[mi][ni][j];
        }
      }
  } else if (n0 >= 4096) {
    // ---- V epilogue: Vt[(col-4096)*2048 + row] = bf16(acc) ----
#pragma unroll
    for (int mi = 0; mi < 4; ++mi)
#pragma unroll
      for (int ni = 0; ni < 4; ++ni) {
        const long vr = n0 - 4096 + wn * 64 + ni * 16 + fr;
#pragma unroll
        for (int j = 0; j < 4; ++j) {
          const long row = m0 + wm * 64 + mi * 16 + rg + j;
          Vt[vr * 2048 + row] = f2bf(acc[mi][ni][j]);
        }
      }
  } else {
    // ---- Q/K epilogue: in-register RoPE via lane-pair shfl ----
    const int isK = (int)(n0 >> 11);
    u16* dstBase = isK ? Kh : Qh;
    const float scl = isK ? 1.0f : Q_PRESCALE;
#pragma unroll
    for (int mi = 0; mi < 4; ++mi)
#pragma unroll
      for (int ni = 0; ni < 4; ++ni) {
        const int col = (int)(n0 & 2047) + wn * 64 + ni * 16 + fr;
        const int hh = col >> 6, d = col & 63, i2 = (col & 63) >> 1;
        const bool odd = d & 1;
#pragma unroll
        for (int j = 0; j < 4; ++j) {
          const int row = (int)m0 + wm * 64 + mi * 16 + rg + j;
          const float v = acc[mi][ni][j];
          const float p = __shfl_xor(v, 1);   // pair partner (col^1, same row)
          const float c = cosT[row * 32 + i2], sn = sinT[row * 32 + i2];
          const float outv = odd ? (p * sn + v * c) : (v * c - p * sn);
          dstBase[((size_t)hh * 2048 + row) * 64 + d] = f2bf(outv * scl);
        }
      }
  }
}

// ---------------- flash attention (causal), dual streams fused + combine ----------------
// 256 blocks x 512 thr (8 waves). Waves 0-3: stream1 (hh=2h), waves 4-7:
// stream2 (hh=2h+1), same 16-row slices. V staged ONCE, shared. At each
// q-tile flush: stream2 waves drop normalized o into LDS Xch, barrier
// (the existing end-of-iter syncthreads), stream1 waves compute
// attn1 - lam*attn2, RMS-norm, *g*(1-li), and store ab bf16 directly.
__global__ __launch_bounds__(512) void attn_kernel(
    const u16* __restrict__ Qh, const u16* __restrict__ Kh,
    const u16* __restrict__ Vt, const float* __restrict__ lam,
    const float* __restrict__ g, u16* __restrict__ ab) {
  __shared__ u16 Kt1[2][64 * 64];     // 16 KiB  stream1 keys (chunk-swizzled)
  __shared__ u16 Kt2[2][64 * 64];     // 16 KiB  stream2 keys
  __shared__ u16 Vs[2][128 * 64];     // 32 KiB  shared V
  __shared__ __bf16 Ps[8 * 16 * 64];  // 16 KiB  per-wave P staging (swizzled)
  __shared__ float Xch[4][16][132];   // ~33 KiB exchange (pad 132: bank-spread)
  const int tid = threadIdx.x, lane = tid & 63, w = tid >> 6;
  const int comp = w >> 2, wq = w & 3;
  const int fr = lane & 15, kgrp = lane >> 4;
  const int bid = blockIdx.x;
  const int xcd = bid & 7, idx = bid >> 3;
  const int h = xcd * 2 + (idx & 1);      // 2 heads per XCD group (L2 locality)
  const int pairIdx = idx >> 1;           // 0..15
  const int q0A = pairIdx * 64, q0B = (31 - pairIdx) * 64;
  const int jmaxA = pairIdx, jmaxB = 31 - pairIdx;
  const int ntA = jmaxA + 1, ntot = ntA + jmaxB + 1;  // == 33
  const size_t hhQ = (size_t)(2 * h + comp);

  const int sr = lane >> 3;
  const int scS = (((lane & 7) ^ sr) * 8);  // source-swizzled column (elems)
  const int swz = (fr & 7) << 3;            // read-side XOR (elems)

  const float lf = *lam;
  float gv[8];
#pragma unroll
  for (int nf = 0; nf < 8; ++nf) gv[nf] = g[nf * 16 + fr];

  bf16x8 qf0, qf1;
  {
    const u16* qb = Qh + (hhQ * 2048 + q0A + wq * 16 + fr) * 64 + kgrp * 8;
    qf0 = *(const bf16x8*)qb;
    qf1 = *(const bf16x8*)(qb + 32);
  }
  bf16x8 onesf;
#pragma unroll
  for (int i = 0; i < 8; ++i) onesf[i] = (__bf16)1.0f;

  // o[0..7] = output d-frags; o[8] = row-sum accumulator (ones-MFMA)
  f32x4 o[9];
#pragma unroll
  for (int i = 0; i < 9; ++i) o[i] = f32x4{0.f, 0.f, 0.f, 0.f};
  float m_r[4] = {-1e30f, -1e30f, -1e30f, -1e30f};

  auto stage = [&](int b, int kv0) {
    gload_lds16(Kh + ((size_t)(2 * h) * 2048 + kv0 + w * 8 + sr) * 64 + scS,
                &Kt1[b][(w * 8) * 64]);
    gload_lds16(Kh + ((size_t)(2 * h + 1) * 2048 + kv0 + w * 8 + sr) * 64 + scS,
                &Kt2[b][(w * 8) * 64]);
#pragma unroll
    for (int i = 0; i < 2; ++i)
      gload_lds16(Vt + ((size_t)h * 128 + w * 16 + i * 8 + sr) * 2048 + kv0 + scS,
                  &Vs[b][(w * 16 + i * 8) * 64]);
  };

  // stream2: publish normalized o into Xch (read by stream1 after barrier)
  auto publish = [&]() {
#pragma unroll
    for (int j = 0; j < 4; ++j) {
      const float inv = 1.0f / o[8][j];
#pragma unroll
      for (int nf = 0; nf < 8; ++nf)
        Xch[wq][kgrp * 4 + j][nf * 16 + fr] = o[nf][j] * inv;
    }
  };
  // stream1: combine + RMS-norm + store ab
  auto combineStore = [&](int q0) {
#pragma unroll
    for (int j = 0; j < 4; ++j) {
      const float inv = 1.0f / o[8][j];
      const int row = q0 + wq * 16 + kgrp * 4 + j;
      float xv[8], ss = 0.f;
#pragma unroll
      for (int nf = 0; nf < 8; ++nf) {
        xv[nf] = o[nf][j] * inv - lf * Xch[wq][kgrp * 4 + j][nf * 16 + fr];
        ss += xv[nf] * xv[nf];
      }
#pragma unroll
      for (int mk = 1; mk < 16; mk <<= 1) ss += __shfl_xor(ss, mk);
      const float r = rsqrtf(ss * (1.0f / 128.0f) + 1e-5f) * ONE_MINUS_LI;
      u16* op = ab + (size_t)row * 2048 + h * 128;
#pragma unroll
      for (int nf = 0; nf < 8; ++nf) op[nf * 16 + fr] = f2bf(xv[nf] * r * gv[nf]);
    }
  };
  auto resetState = [&]() {
#pragma unroll
    for (int i = 0; i < 9; ++i) o[i] = f32x4{0.f, 0.f, 0.f, 0.f};
#pragma unroll
    for (int j = 0; j < 4; ++j) m_r[j] = -1e30f;
  };

  stage(0, 0);
  __syncthreads();

  for (int t = 0; t < ntot; ++t) {
    const int cur = t & 1;
    if (t + 1 < ntot) {
      const int nk = (t + 1 < ntA) ? (t + 1) * 64 : (t + 1 - ntA) * 64;
      stage(cur ^ 1, nk);
    }
    const bool inA = t < ntA;
    const int q0 = inA ? q0A : q0B;
    const int jj = inA ? t : t - ntA;
    const int kv0 = jj * 64;
    const bool diag = inA ? (jj == jmaxA) : (jj == jmaxB);
    const u16* kt = comp ? &Kt2[cur][0] : &Kt1[cur][0];

    // ---- QK^T (scores already scaled, exp2 domain) ----
    f32x4 s[4];
    __builtin_amdgcn_s_setprio(1);
#pragma unroll
    for (int nf = 0; nf < 4; ++nf) {
      s[nf] = f32x4{0.f, 0.f, 0.f, 0.f};
      const bf16x8 b0 = *(const bf16x8*)&kt[(nf * 16 + fr) * 64 + ((kgrp * 8) ^ swz)];
      const bf16x8 b1 = *(const bf16x8*)&kt[(nf * 16 + fr) * 64 + ((32 + kgrp * 8) ^ swz)];
      s[nf] = __builtin_amdgcn_mfma_f32_16x16x32_bf16(qf0, b0, s[nf], 0, 0, 0);
      s[nf] = __builtin_amdgcn_mfma_f32_16x16x32_bf16(qf1, b1, s[nf], 0, 0, 0);
    }
    __builtin_amdgcn_s_setprio(0);

    // ---- mask + row max ----
    float pmax[4] = {-1e30f, -1e30f, -1e30f, -1e30f};
    if (diag) {
#pragma unroll
      for (int nf = 0; nf < 4; ++nf) {
        const int key = kv0 + nf * 16 + fr;
#pragma unroll
        for (int j = 0; j < 4; ++j) {
          float sc2 = s[nf][j];
          if (key > q0 + wq * 16 + kgrp * 4 + j) sc2 = -1e30f;
          s[nf][j] = sc2;
          pmax[j] = fmaxf(pmax[j], sc2);
        }
      }
    } else {
#pragma unroll
      for (int nf = 0; nf < 4; ++nf)
#pragma unroll
        for (int j = 0; j < 4; ++j) pmax[j] = fmaxf(pmax[j], s[nf][j]);
    }
#pragma unroll
    for (int j = 0; j < 4; ++j)
#pragma unroll
      for (int mk = 1; mk < 16; mk <<= 1) pmax[j] = fmaxf(pmax[j], __shfl_xor(pmax[j], mk));

    // ---- defer-rescale (exact: only when a row max grew) ----
    bool grow = false;
#pragma unroll
    for (int j = 0; j < 4; ++j) grow |= (pmax[j] > m_r[j]);
    if (__any(grow)) {
#pragma unroll
      for (int j = 0; j < 4; ++j) {
        const float mn = fmaxf(m_r[j], pmax[j]);
        const float sf = fast_exp2(m_r[j] - mn);
        m_r[j] = mn;
#pragma unroll
        for (int nf = 0; nf < 9; ++nf) o[nf][j] *= sf;
      }
    }

    // ---- exp2 + P staging (swizzled, native bf16 cast) ----
#pragma unroll
    for (int nf = 0; nf < 4; ++nf)
#pragma unroll
      for (int j = 0; j < 4; ++j) {
        const float p = fast_exp2(s[nf][j] - m_r[j]);
        const int prow = kgrp * 4 + j;
        Ps[w * 1024 + prow * 64 + ((nf * 16 + fr) ^ ((prow & 7) << 3))] = (__bf16)p;
      }

    // ---- PV (+ ones-MFMA row-sum into o[8]) ----
    const bf16x8 pa0 = *(const bf16x8*)&Ps[w * 1024 + fr * 64 + ((kgrp * 8) ^ swz)];
    const bf16x8 pa1 = *(const bf16x8*)&Ps[w * 1024 + fr * 64 + ((32 + kgrp * 8) ^ swz)];
    __builtin_amdgcn_s_setprio(1);
#pragma unroll
    for (int nf = 0; nf < 8; ++nf) {
      const bf16x8 v0 = *(const bf16x8*)&Vs[cur][(nf * 16 + fr) * 64 + ((kgrp * 8) ^ swz)];
      const bf16x8 v1 =
          *(const bf16x8*)&Vs[cur][(nf * 16 + fr) * 64 + ((32 + kgrp * 8) ^ swz)];
      o[nf] = __builtin_amdgcn_mfma_f32_16x16x32_bf16(pa0, v0, o[nf], 0, 0, 0);
      o[nf] = __builtin_amdgcn_mfma_f32_16x16x32_bf16(pa1, v1, o[nf], 0, 0, 0);
    }
    o[8] = __builtin_amdgcn_mfma_f32_16x16x32_bf16(pa0, onesf, o[8], 0, 0, 0);
    o[8] = __builtin_amdgcn_mfma_f32_16x16x32_bf16(pa1, onesf, o[8], 0, 0, 0);
    __builtin_amdgcn_s_setprio(0);

    // ---- tile-A flush: stream2 publishes BEFORE the barrier ----
    if (t == jmaxA && comp == 1) publish();
    __syncthreads();
    if (t == jmaxA) {
      if (comp == 0) combineStore(q0A);
      resetState();
      const u16* qb = Qh + (hhQ * 2048 + q0B + wq * 16 + fr) * 64 + kgrp * 8;
      qf0 = *(const bf16x8*)qb;
      qf1 = *(const bf16x8*)(qb + 32);
    }
  }
  // ---- tile-B flush ----
  if (comp == 1) publish();
  __syncthreads();
  if (comp == 0) combineStore(q0B);
}

extern "C" void kernel_launch(void* const* d_in, const int* in_sizes, int n_in,
                              void* d_out, int out_size, void* d_ws, size_t ws_size,
                              hipStream_t stream) {
  const float* x = (const float*)d_in[0];
  const float* Wq = (const float*)d_in[1];
  const float* Wk = (const float*)d_in[2];
  const float* Wv = (const float*)d_in[3];
  const float* Wo = (const float*)d_in[4];
  const float* lq1 = (const float*)d_in[5];
  const float* lk1 = (const float*)d_in[6];
  const float* lq2 = (const float*)d_in[7];
  const float* lk2 = (const float*)d_in[8];
  const float* g = (const float*)d_in[9];
  float* out = (float*)d_out;

  char* ws = (char*)d_ws;
  u16* xb = (u16*)(ws);                                 // 8 MiB
  u16* WqkvT = (u16*)(ws + (size_t)(8u << 20));         // 24 MiB
  u16* WoT = (u16*)(ws + (size_t)(32u << 20));          // 8 MiB
  u16* Qh = (u16*)(ws + (size_t)(88u << 20));           // 8 MiB
  u16* Kh = (u16*)(ws + (size_t)(96u << 20));           // 8 MiB
  u16* Vt = (u16*)(ws + (size_t)(104u << 20));          // 8 MiB
  u16* ab = (u16*)(ws + (size_t)(112u << 20));          // 8 MiB
  float* cosT = (float*)(ws + (size_t)(120u << 20));    // 256 KiB
  float* sinT = (float*)(ws + (size_t)(120u << 20) + (256u << 10));
  float* lam = (float*)(ws + (size_t)(120u << 20) + (512u << 10));

  prep_kernel<<<16384 + 4096 + 256 + 1, 256, 0, stream>>>(
      x, Wq, Wk, Wv, Wo, lq1, lk1, lq2, lk2, xb, WqkvT, WoT, cosT, sinT, lam);
  gemm_bt_kernel<<<dim3(48, 16), 256, 0, stream>>>(xb, WqkvT, nullptr, 2048, 6144, 2048,
                                                   1, cosT, sinT, Qh, Kh, Vt);
  attn_kernel<<<256, 512, 0, stream>>>(Qh, Kh, Vt, lam, g, ab);
  gemm_bt_kernel<<<dim3(16, 16), 256, 0, stream>>>(ab, WoT, out, 2048, 2048, 2048,
                                                   0, nullptr, nullptr, nullptr, nullptr,
                                                   nullptr);
}